// Round 14
// baseline (253.162 us; speedup 1.0000x reference)
//
#include <hip/hip_runtime.h>

#define T_LEN 1024
#define NBATCH 256
#define HDIM 12
#define PAIR_STRIDE 12288  // 256*48 dwords per timestep-pair
#define X3_TB 16           // padded halves per (t,b)

typedef __fp16 fp16x2 __attribute__((ext_vector_type(2)));

// ---------- helpers ----------
#if __has_builtin(__builtin_amdgcn_exp2f)
#define EXP2F(x) __builtin_amdgcn_exp2f(x)
#else
#define EXP2F(x) exp2f(x)
#endif
#if __has_builtin(__builtin_amdgcn_rcpf)
#define RCPF(x) __builtin_amdgcn_rcpf(x)
#else
#define RCPF(x) (1.0f / (x))
#endif

#define KSIG -1.4426950408889634f
#define KTAN -2.8853900817779268f

__device__ __forceinline__ unsigned bperm(int byteidx, unsigned v) {
#if __has_builtin(__builtin_amdgcn_ds_bpermute)
  return (unsigned)__builtin_amdgcn_ds_bpermute(byteidx, (int)v);
#else
  return (unsigned)__shfl((int)v, byteidx >> 2, 64);
#endif
}

template <int Q>
__device__ __forceinline__ float qb(float v) {
#if __has_builtin(__builtin_amdgcn_mov_dpp)
  return __int_as_float(__builtin_amdgcn_mov_dpp(__float_as_int(v), Q * 0x55, 0xF, 0xF, true));
#else
  return __shfl(v, (threadIdx.x & ~3) | Q, 64);
#endif
}

// lane i <- lane i-4 within 16-lane row
__device__ __forceinline__ float row_shr4(float v) {
#if __has_builtin(__builtin_amdgcn_mov_dpp)
  return __int_as_float(__builtin_amdgcn_mov_dpp(__float_as_int(v), 0x114, 0xF, 0xF, true));
#else
  return __shfl(v, (threadIdx.x & 63) - 4, 64);
#endif
}

__device__ __forceinline__ float h16tof(unsigned short u) {
  union { unsigned short s; _Float16 h; } c; c.s = u; return (float)c.h;
}
__device__ __forceinline__ unsigned short f16bits(float f) {
  union { unsigned short s; _Float16 h; } c; c.h = (_Float16)f; return c.s;
}
__device__ __forceinline__ float h16lo(unsigned u) {
  union { unsigned short s; _Float16 h; } c; c.s = (unsigned short)(u & 0xffffu); return (float)c.h;
}
__device__ __forceinline__ float h16hi(unsigned u) {
  union { unsigned short s; _Float16 h; } c; c.s = (unsigned short)(u >> 16); return (float)c.h;
}
__device__ __forceinline__ unsigned pk16(float a, float b) {
#if __has_builtin(__builtin_amdgcn_cvt_pkrtz)
  fp16x2 h = __builtin_amdgcn_cvt_pkrtz(a, b);
  return __builtin_bit_cast(unsigned, h);
#else
  return (unsigned)f16bits(a) | ((unsigned)f16bits(b) << 16);
#endif
}

__device__ __forceinline__ float dot2acc(unsigned a, unsigned b, float c) {
#if __has_builtin(__builtin_amdgcn_fdot2)
  return __builtin_amdgcn_fdot2(__builtin_bit_cast(fp16x2, a), __builtin_bit_cast(fp16x2, b), c, false);
#else
  return fmaf(h16lo(a), h16lo(b), fmaf(h16hi(a), h16hi(b), c));
#endif
}

// 3-deep dot2 chain (6 MACs)
__device__ __forceinline__ float d3(const unsigned* w, const unsigned* h, float init) {
  float a = dot2acc(w[0], h[0], init);
  a = dot2acc(w[1], h[1], a);
  return dot2acc(w[2], h[2], a);
}

// gate nonlin (prescaled input) + c/h update; i,f,g,o quad-broadcast via DPP
__device__ __forceinline__ float nlup(float av, float& cv, float c1, float c0) {
  float e = EXP2F(av);
  float n = fmaf(c1, RCPF(1.f + e), c0);
  float si = qb<0>(n), sf = qb<1>(n), tg = qb<2>(n), so = qb<3>(n);
  cv = fmaf(sf, cv, si * tg);
  float e2 = EXP2F(KTAN * cv);
  return so * fmaf(2.f, RCPF(1.f + e2), -1.f);
}
// pack h into 6 broadcast f16x2 pairs via ds_bpermute (LDS pipe, off-VALU)
__device__ __forceinline__ unsigned packb(float hq, unsigned* hp) {
  float sh = row_shr4(hq);
  unsigned pkv = pk16(sh, hq);
  hp[0] = bperm(16, pkv);  hp[1] = bperm(48, pkv);  hp[2] = bperm(80, pkv);
  hp[3] = bperm(112, pkv); hp[4] = bperm(144, pkv); hp[5] = bperm(176, pkv);
  return pkv;
}

// LDS-drain + barrier WITHOUT vmcnt(0): global stores stay in flight.
#define BARRIER_LGKM() asm volatile("s_waitcnt lgkmcnt(0)\n\ts_barrier" ::: "memory")

// ============================================================================
// Kernel 0: (a) pregate pairs pg2[t2][b][lane48]; (b) packs: w2, WI, w1 -> f16.
// ============================================================================
__global__ __launch_bounds__(64, 4) void pregate_kernel(
    const float* __restrict__ mfcc, const float* __restrict__ Wih,
    const float* __restrict__ bih, const float* __restrict__ bhh,
    const float* __restrict__ w2, const float* __restrict__ WI,
    const float* __restrict__ w1, unsigned* __restrict__ pg2,
    unsigned* __restrict__ w2pk, unsigned* __restrict__ wipk,
    unsigned* __restrict__ w1pk) {
  if (blockIdx.x >= 2048) {  // pack blocks
    const int base = (blockIdx.x - 2048) * 64 + threadIdx.x;
    for (int i = base; i < 4096; i += 512) {  // w2: [32 kp][128 c]
      int kp = i >> 7, c = i & 127;
      float2 v = ((const float2*)w2)[c * 32 + kp];
      w2pk[i] = pk16(v.x, v.y);
    }
    for (int i = base; i < 432; i += 512) {   // WI: [k6][e][6 dp], pairs over d
      int k6 = i / 72, rem = i % 72, e = rem / 6, dp = rem % 6;
      wipk[i] = pk16(WI[k6 * 144 + (2 * dp) * HDIM + e],
                     WI[k6 * 144 + (2 * dp + 1) * HDIM + e]);
    }
    for (int i = base; i < 384; i += 512) {   // w1: [64 ch][6 dp]
      int ch = i / 6, dp = i % 6;
      float2 v = ((const float2*)w1)[ch * 6 + dp];
      w1pk[i] = pk16(v.x, v.y);
    }
    return;
  }
  const int b = blockIdx.x & 255;
  const int tc = blockIdx.x >> 8;  // 0..7, chunks of 64 pairs
  const int lane = threadIdx.x;
  const int j = lane >> 2, q = lane & 3;
  const int jj = (j < HDIM) ? j : (HDIM - 1);
  const int g = q * HDIM + jj;
  const float kqv = (q == 2) ? KTAN : KSIG;
  float w[HDIM];
#pragma unroll
  for (int m = 0; m < HDIM; ++m) w[m] = kqv * Wih[g * HDIM + m];
  const float bias = kqv * (bih[g] + bhh[g]);
  const bool wr = (lane < 48);
  const float* xb = mfcc + (b * T_LEN + tc * 128) * HDIM;
  unsigned* out = pg2 + (unsigned)(tc * 64 * NBATCH + b) * 48 + lane;
  for (int tp = 0; tp < 64; ++tp) {
    float a0 = bias, a1 = bias;
#pragma unroll
    for (int d = 0; d < HDIM; ++d) {
      a0 = fmaf(w[d], xb[d], a0);
      a1 = fmaf(w[d], xb[HDIM + d], a1);
    }
    if (wr) *out = pk16(a0, a1);
    xb += 2 * HDIM;
    out += PAIR_STRIDE;
  }
}

// ============================================================================
// Kernel 1: 3-layer LSTM (R13-proven). 3 waves/block, layer per wave, depth-8
// supersteps, lgkm-only barriers, hoisted input dots, 1280B LDS dbuf.
// ============================================================================
__global__ __launch_bounds__(192, 1) void lstm3_kernel(
    const unsigned* __restrict__ pg2,
    const float* __restrict__ Wih, const float* __restrict__ Whh,
    const float* __restrict__ bih, const float* __restrict__ bhh,
    unsigned short* __restrict__ x3) {
  __shared__ __align__(16) unsigned ldsb[320];
  const int b = blockIdx.x;
  const int tid = threadIdx.x;
  const int wid = tid >> 6;
  const int lane = tid & 63;
  const int j = lane >> 2, q = lane & 3;
  const int jj = (j < HDIM) ? j : (HDIM - 1);
  const int g = q * HDIM + jj;
  const float kqv = (q == 2) ? KTAN : KSIG;
  const float c1c = (q == 2) ? 2.0f : 1.0f;
  const float c0c = (q == 2) ? -1.0f : 0.0f;

  const int row = (wid * 48 + g) * HDIM;
  unsigned wihp[6], whhp[6];
#pragma unroll
  for (int m = 0; m < 6; ++m) {
    wihp[m] = pk16(kqv * Wih[row + 2 * m], kqv * Wih[row + 2 * m + 1]);
    whhp[m] = pk16(kqv * Whh[row + 2 * m], kqv * Whh[row + 2 * m + 1]);
  }
  const float biasw = kqv * (bih[wid * 48 + g] + bhh[wid * 48 + g]);

  float cv = 0.f;
  unsigned hown[6] = {0, 0, 0, 0, 0, 0};

  const int grpi = lane >> 3;
  const bool wvalid = ((lane & 7) == 7) && (grpi < 6);
  const int wlayer = (wid == 0) ? 0 : 64;
  const int wsl = wvalid ? (wlayer + grpi) : (256 + lane);
  const int wst = wvalid ? 8 : 0;

  const int lane_src = (lane < 48) ? lane : (44 + (lane & 3));
  const char* pgbase = (const char*)(pg2 + (unsigned)b * 48);
  const unsigned PGB = PAIR_STRIDE * 4;
  const unsigned PGLIM = 513u * PGB;
  uint4 P0 = {0, 0, 0, 0}, P1 = P0, A0 = P0, A1 = P0;
  unsigned pg_upos = 0;
  if (wid == 0) {
    P0.x = *(const unsigned*)(pgbase + 0 * PGB + lane_src * 4);
    P0.y = *(const unsigned*)(pgbase + 1 * PGB + lane_src * 4);
    P0.z = *(const unsigned*)(pgbase + 2 * PGB + lane_src * 4);
    P0.w = *(const unsigned*)(pgbase + 3 * PGB + lane_src * 4);
    P1.x = *(const unsigned*)(pgbase + 4 * PGB + lane_src * 4);
    P1.y = *(const unsigned*)(pgbase + 5 * PGB + lane_src * 4);
    P1.z = *(const unsigned*)(pgbase + 6 * PGB + lane_src * 4);
    P1.w = *(const unsigned*)(pgbase + 7 * PGB + lane_src * 4);
    A0.x = *(const unsigned*)(pgbase + 8 * PGB + lane_src * 4);
    A0.y = *(const unsigned*)(pgbase + 9 * PGB + lane_src * 4);
    A0.z = *(const unsigned*)(pgbase + 10 * PGB + lane_src * 4);
    A0.w = *(const unsigned*)(pgbase + 11 * PGB + lane_src * 4);
    A1.x = *(const unsigned*)(pgbase + 12 * PGB + lane_src * 4);
    A1.y = *(const unsigned*)(pgbase + 13 * PGB + lane_src * 4);
    A1.z = *(const unsigned*)(pgbase + 14 * PGB + lane_src * 4);
    A1.w = *(const unsigned*)(pgbase + 15 * PGB + lane_src * 4);
    pg_upos = 16u * PGB;
  }

  char* x3b = (char*)(x3 + (unsigned)b * X3_TB);
  const int x3_loff = ((j & 1) && j < HDIM) ? (j - 1) * 2 : ((j < HDIM) ? 24 : 28);
  unsigned x3_upos = 0;
  const unsigned X3STEP = NBATCH * X3_TB * 2;

  auto l0_ss = [&](int par, uint4 P) {
    const int wpb = wvalid ? par * 128 : 0;
    const float pgf[8] = {h16lo(P.x), h16hi(P.x), h16lo(P.y), h16hi(P.y),
                          h16lo(P.z), h16hi(P.z), h16lo(P.w), h16hi(P.w)};
#pragma unroll
    for (int st = 0; st < 8; ++st) {
      float a = d3(whhp, hown, pgf[st]) + d3(whhp + 3, hown + 3, 0.f);
      float hq = nlup(a, cv, c1c, c0c);
      unsigned pkv = packb(hq, hown);
      ldsb[wpb + wsl + st * wst] = pkv;
    }
  };
  auto l1_ss = [&](int par) {
    const unsigned* rb = ldsb + (par ^ 1) * 128;
    unsigned hin[8][6];
#pragma unroll
    for (int st = 0; st < 8; ++st) {
      uint4 A = *(const uint4*)(rb + st * 8);
      uint2 B = *(const uint2*)(rb + st * 8 + 4);
      hin[st][0] = A.x; hin[st][1] = A.y; hin[st][2] = A.z;
      hin[st][3] = A.w; hin[st][4] = B.x; hin[st][5] = B.y;
    }
    float aI[8];
#pragma unroll
    for (int st = 0; st < 8; ++st)
      aI[st] = d3(wihp, hin[st], biasw) + d3(wihp + 3, hin[st] + 3, 0.f);
    const int wpb = wvalid ? par * 128 : 0;
#pragma unroll
    for (int st = 0; st < 8; ++st) {
      float a = aI[st] + (d3(whhp, hown, 0.f) + d3(whhp + 3, hown + 3, 0.f));
      float hq = nlup(a, cv, c1c, c0c);
      unsigned pkv = packb(hq, hown);
      ldsb[wpb + wsl + st * wst] = pkv;
    }
  };
  auto l2_ss = [&](int par) {
    const unsigned* rb = ldsb + (par ^ 1) * 128 + 64;
    unsigned hin[8][6];
#pragma unroll
    for (int st = 0; st < 8; ++st) {
      uint4 A = *(const uint4*)(rb + st * 8);
      uint2 B = *(const uint2*)(rb + st * 8 + 4);
      hin[st][0] = A.x; hin[st][1] = A.y; hin[st][2] = A.z;
      hin[st][3] = A.w; hin[st][4] = B.x; hin[st][5] = B.y;
    }
    float aI[8];
#pragma unroll
    for (int st = 0; st < 8; ++st)
      aI[st] = d3(wihp, hin[st], biasw) + d3(wihp + 3, hin[st] + 3, 0.f);
#pragma unroll
    for (int st = 0; st < 8; ++st) {
      float a = aI[st] + (d3(whhp, hown, 0.f) + d3(whhp + 3, hown + 3, 0.f));
      float hq = nlup(a, cv, c1c, c0c);
      unsigned pkv = packb(hq, hown);
      *(unsigned*)(x3b + x3_upos + st * X3STEP + x3_loff) = pkv;
    }
    x3_upos += 8 * X3STEP;
  };

  if (wid == 0) l0_ss(0, P0);
  BARRIER_LGKM();
  if (wid == 0) l0_ss(1, P1);
  else if (wid == 1) l1_ss(1);
  BARRIER_LGKM();
  for (int i = 0; i < 63; ++i) {
    uint4 N0 = {0, 0, 0, 0}, N1 = N0;
    if (wid == 0) {
      unsigned o0 = pg_upos, o1 = o0 + PGB, o2 = o0 + 2 * PGB, o3 = o0 + 3 * PGB;
      unsigned o4 = o0 + 4 * PGB, o5 = o0 + 5 * PGB, o6 = o0 + 6 * PGB, o7 = o0 + 7 * PGB;
      o0 = o0 > PGLIM ? PGLIM : o0; o1 = o1 > PGLIM ? PGLIM : o1;
      o2 = o2 > PGLIM ? PGLIM : o2; o3 = o3 > PGLIM ? PGLIM : o3;
      o4 = o4 > PGLIM ? PGLIM : o4; o5 = o5 > PGLIM ? PGLIM : o5;
      o6 = o6 > PGLIM ? PGLIM : o6; o7 = o7 > PGLIM ? PGLIM : o7;
      N0.x = *(const unsigned*)(pgbase + o0 + lane_src * 4);
      N0.y = *(const unsigned*)(pgbase + o1 + lane_src * 4);
      N0.z = *(const unsigned*)(pgbase + o2 + lane_src * 4);
      N0.w = *(const unsigned*)(pgbase + o3 + lane_src * 4);
      N1.x = *(const unsigned*)(pgbase + o4 + lane_src * 4);
      N1.y = *(const unsigned*)(pgbase + o5 + lane_src * 4);
      N1.z = *(const unsigned*)(pgbase + o6 + lane_src * 4);
      N1.w = *(const unsigned*)(pgbase + o7 + lane_src * 4);
      pg_upos += 8 * PGB;
      l0_ss(0, A0);
    } else if (wid == 1) {
      l1_ss(0);
    } else {
      l2_ss(0);
    }
    BARRIER_LGKM();
    if (wid == 0) l0_ss(1, A1);
    else if (wid == 1) l1_ss(1);
    else l2_ss(1);
    BARRIER_LGKM();
    if (wid == 0) { A0 = N0; A1 = N1; }
  }
  if (wid == 1) l1_ss(0);
  else if (wid == 2) l2_ss(0);
  BARRIER_LGKM();
  if (wid == 2) l2_ss(1);
}

// ============================================================================
// Kernel 2: per-timestep MLP + batch BN + lambda projection. 1 block / t,
// 256 threads, 3 blocks/CU. fc2 tiled 8b x 8c x 2 c-passes (acc=64 VGPR);
// w2 pairs read from GLOBAL (L2-hot); lambda partials shfl-paired -> f16 LDS;
// lm[6] persists in regs. lgkm-only barriers throughout.
// ============================================================================
__global__ __launch_bounds__(256, 3) void mlp_out_kernel(
    const unsigned short* __restrict__ x3, const float* __restrict__ mfcc,
    const unsigned* __restrict__ w1pk, const float* __restrict__ g1,
    const float* __restrict__ be1, const unsigned* __restrict__ w2pk,
    const float* __restrict__ g2, const float* __restrict__ be2,
    const float* __restrict__ w3, const float* __restrict__ b3,
    const unsigned* __restrict__ wipk, float* __restrict__ outp) {
  __shared__ __align__(16) unsigned char smem[49856];
  unsigned* h1p = (unsigned*)smem;            // [32][256] dwords, 32KB
  unsigned* p3h = (unsigned*)(smem + 32768);  // [4][256][3] f16-pair dw, 12KB
  float* stp = (float*)(smem + 45056);        // 2KB partials
  float* scsh = (float*)(smem + 47104);       // [128][2] f32, 1KB
  unsigned* wis = (unsigned*)(smem + 48128);  // [432] WI pairs, 1728B

  const int t = blockIdx.x;
  const int tid = threadIdx.x;

  // ---- stage wipk ----
  for (int i = tid; i < 432; i += 256) wis[i] = wipk[i];

  // ---- fc1 via dot2 on native f16 d-pairs (bias cancels under BN) ----
  {
    const unsigned short* xp = x3 + t * (NBATCH * X3_TB) + tid * X3_TB;
    uint2 u0 = ((const uint2*)xp)[0];
    uint2 u1 = ((const uint2*)xp)[1];
    uint2 u2 = ((const uint2*)xp)[2];
    const unsigned u[6] = {u0.x, u0.y, u1.x, u1.y, u2.x, u2.y};
#pragma unroll 4
    for (int kp = 0; kp < 32; ++kp) {
      const unsigned* wp = w1pk + kp * 12;  // rows 2kp, 2kp+1
      float a0 = dot2acc(wp[0], u[0], 0.f);
      float a1 = dot2acc(wp[6], u[0], 0.f);
#pragma unroll
      for (int dp = 1; dp < 6; ++dp) {
        a0 = dot2acc(wp[dp], u[dp], a0);
        a1 = dot2acc(wp[6 + dp], u[dp], a1);
      }
      h1p[kp * 256 + tid] = pk16(a0, a1);
    }
  }
  BARRIER_LGKM();

  // ---- BN1 stats; thread=(kp,seg), 32 b each, xor32 + LDS reduce ----
  {
    const int kp = tid & 31, seg = tid >> 5;
    const uint4* rp = (const uint4*)(h1p + kp * 256 + seg * 32);
    float sl = 0.f, sh = 0.f, ql = 0.f, qh = 0.f;
#pragma unroll
    for (int i = 0; i < 8; ++i) {
      uint4 v = rp[(i + kp) & 7];
      float f0 = h16lo(v.x), f1 = h16hi(v.x), f2 = h16lo(v.y), f3 = h16hi(v.y);
      float f4 = h16lo(v.z), f5 = h16hi(v.z), f6 = h16lo(v.w), f7 = h16hi(v.w);
      sl += (f0 + f2) + (f4 + f6);
      sh += (f1 + f3) + (f5 + f7);
      ql = fmaf(f0, f0, ql); ql = fmaf(f2, f2, ql); ql = fmaf(f4, f4, ql); ql = fmaf(f6, f6, ql);
      qh = fmaf(f1, f1, qh); qh = fmaf(f3, f3, qh); qh = fmaf(f5, f5, qh); qh = fmaf(f7, f7, qh);
    }
    sl += __shfl_xor(sl, 32, 64); sh += __shfl_xor(sh, 32, 64);
    ql += __shfl_xor(ql, 32, 64); qh += __shfl_xor(qh, 32, 64);
    if ((tid & 63) < 32) {
      float* sp = stp + kp * 16 + (tid >> 6) * 4;
      sp[0] = sl; sp[1] = sh; sp[2] = ql; sp[3] = qh;
    }
  }
  BARRIER_LGKM();
  if (tid < 64) {
    const int kp = tid >> 1, par = tid & 1;
    float s = 0.f, qq = 0.f;
#pragma unroll
    for (int w = 0; w < 4; ++w) {
      s += stp[kp * 16 + w * 4 + par];
      qq += stp[kp * 16 + w * 4 + 2 + par];
    }
    const int ch = 2 * kp + par;
    float mu = s * (1.f / 256.f);
    float var = fmaf(-mu, mu, qq * (1.f / 256.f));
    float sc = g1[ch] * rsqrtf(var + 1e-5f);
    scsh[ch * 2] = sc;
    scsh[ch * 2 + 1] = fmaf(-sc, mu, be1[ch]);
  }
  BARRIER_LGKM();
  // ---- apply BN1 + relu in place (thread = b) ----
  {
    unsigned* cp = h1p + tid;
#pragma unroll 8
    for (int kp = 0; kp < 32; ++kp) {
      unsigned v = cp[kp * 256];
      float fl = fmaxf(fmaf(scsh[kp * 4 + 0], h16lo(v), scsh[kp * 4 + 1]), 0.f);
      float fh = fmaxf(fmaf(scsh[kp * 4 + 2], h16hi(v), scsh[kp * 4 + 3]), 0.f);
      cp[kp * 256] = pk16(fl, fh);
    }
  }
  BARRIER_LGKM();

  // ---- fc2/BN2/fc3 over two c-passes ----
  const int tb = tid & 31, tc2 = tid >> 5;  // b-group, c-group(0..7)
  const int b0 = tb * 8;
  float lm[6];
#pragma unroll
  for (int k6 = 0; k6 < 6; ++k6) lm[k6] = b3[k6];

  for (int p = 0; p < 2; ++p) {
    const int c0 = p * 64 + tc2 * 8;
    float acc[8][8];
#pragma unroll
    for (int bi = 0; bi < 8; ++bi)
#pragma unroll
      for (int ci = 0; ci < 8; ++ci) acc[bi][ci] = 0.f;

    for (int kp = 0; kp < 32; ++kp) {
      const unsigned* hrow = h1p + kp * 256 + b0;
      uint4 a01 = ((const uint4*)hrow)[0];
      uint4 a23 = ((const uint4*)hrow)[1];
      const unsigned ap[8] = {a01.x, a01.y, a01.z, a01.w, a23.x, a23.y, a23.z, a23.w};
      const unsigned* wrow = w2pk + kp * 128 + c0;  // global, L2-hot
      uint4 wv0 = ((const uint4*)wrow)[0];
      uint4 wv1 = ((const uint4*)wrow)[1];
      const unsigned ww[8] = {wv0.x, wv0.y, wv0.z, wv0.w, wv1.x, wv1.y, wv1.z, wv1.w};
#pragma unroll
      for (int bi = 0; bi < 8; ++bi)
#pragma unroll
        for (int ci = 0; ci < 8; ++ci)
          acc[bi][ci] = dot2acc(ap[bi], ww[ci], acc[bi][ci]);
    }

    // BN2 stats for this c-half (shuffle-reduce over tb within 32-lane halves)
    {
      float sv[8], qv[8];
#pragma unroll
      for (int ci = 0; ci < 8; ++ci) {
        float s = 0.f, sq = 0.f;
#pragma unroll
        for (int bi = 0; bi < 8; ++bi) {
          s += acc[bi][ci];
          sq = fmaf(acc[bi][ci], acc[bi][ci], sq);
        }
        sv[ci] = s; qv[ci] = sq;
      }
#pragma unroll
      for (int m = 1; m <= 16; m <<= 1) {
#pragma unroll
        for (int ci = 0; ci < 8; ++ci) {
          sv[ci] += __shfl_xor(sv[ci], m, 64);
          qv[ci] += __shfl_xor(qv[ci], m, 64);
        }
      }
      if (tb == 0) {
#pragma unroll
        for (int ci = 0; ci < 8; ++ci) {
          stp[(c0 + ci) * 2] = sv[ci];
          stp[(c0 + ci) * 2 + 1] = qv[ci];
        }
      }
    }
    BARRIER_LGKM();
    if (tid < 64) {
      const int ch = p * 64 + tid;
      float mu = stp[ch * 2] * (1.f / 256.f);
      float var = fmaf(-mu, mu, stp[ch * 2 + 1] * (1.f / 256.f));
      float sc = g2[ch] * rsqrtf(var + 1e-5f);
      scsh[ch * 2] = sc;
      scsh[ch * 2 + 1] = fmaf(-sc, mu, be2[ch]);
    }
    BARRIER_LGKM();

    // BN2-apply + relu + fc3 partials; pair-combine via shfl_xor(32)
    {
      float lam[8][6];
#pragma unroll
      for (int bi = 0; bi < 8; ++bi)
#pragma unroll
        for (int k6 = 0; k6 < 6; ++k6) lam[bi][k6] = 0.f;
#pragma unroll
      for (int ci = 0; ci < 8; ++ci) {
        const float sc = scsh[(c0 + ci) * 2], shv = scsh[(c0 + ci) * 2 + 1];
        float wv6[6];
#pragma unroll
        for (int k6 = 0; k6 < 6; ++k6) wv6[k6] = w3[k6 * 128 + c0 + ci];
#pragma unroll
        for (int bi = 0; bi < 8; ++bi) {
          float v = fmaxf(fmaf(sc, acc[bi][ci], shv), 0.f);
#pragma unroll
          for (int k6 = 0; k6 < 6; ++k6)
            lam[bi][k6] = fmaf(v, wv6[k6], lam[bi][k6]);
        }
      }
#pragma unroll
      for (int bi = 0; bi < 8; ++bi)
#pragma unroll
        for (int k6 = 0; k6 < 6; ++k6)
          lam[bi][k6] += __shfl_xor(lam[bi][k6], 32, 64);
      if ((tc2 & 1) == 0) {
        const int gg = tc2 >> 1;
#pragma unroll
        for (int bi = 0; bi < 8; ++bi) {
          p3h[gg * 768 + (b0 + bi) * 3 + 0] = pk16(lam[bi][0], lam[bi][1]);
          p3h[gg * 768 + (b0 + bi) * 3 + 1] = pk16(lam[bi][2], lam[bi][3]);
          p3h[gg * 768 + (b0 + bi) * 3 + 2] = pk16(lam[bi][4], lam[bi][5]);
        }
      }
    }
    BARRIER_LGKM();
    // accumulate lambda for this pass (thread = b = tid)
    {
#pragma unroll
      for (int gg = 0; gg < 4; ++gg) {
#pragma unroll
        for (int d = 0; d < 3; ++d) {
          unsigned v = p3h[gg * 768 + tid * 3 + d];
          lm[2 * d] += h16lo(v);
          lm[2 * d + 1] += h16hi(v);
        }
      }
    }
    BARRIER_LGKM();  // protects p3h reuse by pass 2
  }

  // ---- projection: out = x + sum_k lm_k * (x @ WI_k), dot2 via packed WI ----
  {
    const float4* mp = (const float4*)(mfcc + (tid * T_LEN + t) * HDIM);
    float4 m0 = mp[0], m1 = mp[1], m2 = mp[2];
    const float x[HDIM] = {m0.x, m0.y, m0.z, m0.w, m1.x, m1.y,
                           m1.z, m1.w, m2.x, m2.y, m2.z, m2.w};
    unsigned xpk[6];
#pragma unroll
    for (int dp = 0; dp < 6; ++dp) xpk[dp] = pk16(x[2 * dp], x[2 * dp + 1]);
    float o[HDIM];
#pragma unroll
    for (int e = 0; e < HDIM; ++e) o[e] = x[e];
#pragma unroll
    for (int k6 = 0; k6 < 6; ++k6) {
      const unsigned* wrow = wis + k6 * 72;
#pragma unroll
      for (int e = 0; e < HDIM; ++e) {
        float s = dot2acc(xpk[0], wrow[e * 6 + 0], 0.f);
        s = dot2acc(xpk[1], wrow[e * 6 + 1], s);
        s = dot2acc(xpk[2], wrow[e * 6 + 2], s);
        s = dot2acc(xpk[3], wrow[e * 6 + 3], s);
        s = dot2acc(xpk[4], wrow[e * 6 + 4], s);
        s = dot2acc(xpk[5], wrow[e * 6 + 5], s);
        o[e] = fmaf(lm[k6], s, o[e]);
      }
    }
    float4* op4 = (float4*)(outp + (tid * T_LEN + t) * HDIM);
    op4[0] = make_float4(o[0], o[1], o[2], o[3]);
    op4[1] = make_float4(o[4], o[5], o[6], o[7]);
    op4[2] = make_float4(o[8], o[9], o[10], o[11]);
  }
}

// ============================================================================
extern "C" void kernel_launch(void* const* d_in, const int* in_sizes, int n_in,
                              void* d_out, int out_size, void* d_ws, size_t ws_size,
                              hipStream_t stream) {
  const float* mfcc = (const float*)d_in[0];
  const float* Wih = (const float*)d_in[1];
  const float* Whh = (const float*)d_in[2];
  const float* bih = (const float*)d_in[3];
  const float* bhh = (const float*)d_in[4];
  const float* w1 = (const float*)d_in[5];
  const float* g1 = (const float*)d_in[7];
  const float* be1 = (const float*)d_in[8];
  const float* w2 = (const float*)d_in[9];
  const float* g2 = (const float*)d_in[11];
  const float* be2 = (const float*)d_in[12];
  const float* w3 = (const float*)d_in[13];
  const float* b3 = (const float*)d_in[14];
  const float* WI = (const float*)d_in[15];

  // ws: pg2 dwords [514 pairs][256 b][48] = 25,264,128 B;
  //     x3 f16 [1024][256][16] = 8,388,608 B @ 25,264,128;
  //     w2pk [4096] dw @ 33,652,736; wipk [432] dw @ 33,669,120;
  //     w1pk [384] dw @ 33,670,848.
  unsigned* pg2 = (unsigned*)d_ws;
  unsigned short* x3 = (unsigned short*)((char*)d_ws + 25264128);
  unsigned* w2pk = (unsigned*)((char*)d_ws + 33652736);
  unsigned* wipk = (unsigned*)((char*)d_ws + 33669120);
  unsigned* w1pk = (unsigned*)((char*)d_ws + 33670848);
  float* out = (float*)d_out;

  hipLaunchKernelGGL(pregate_kernel, dim3(2056), dim3(64), 0, stream,
                     mfcc, Wih, bih, bhh, w2, WI, w1, pg2, w2pk, wipk, w1pk);
  hipLaunchKernelGGL(lstm3_kernel, dim3(NBATCH), dim3(192), 0, stream,
                     pg2, Wih, Whh, bih, bhh, x3);
  hipLaunchKernelGGL(mlp_out_kernel, dim3(T_LEN), dim3(256), 0, stream,
                     x3, mfcc, w1pk, g1, be1, w2pk, g2, be2, w3, b3, wipk, out);
}

// Round 15
// 227.435 us; speedup vs baseline: 1.1131x; 1.1131x over previous
//
#include <hip/hip_runtime.h>

#define T_LEN 1024
#define NBATCH 256
#define HDIM 12
#define PAIR_STRIDE 12288  // 256*48 dwords per timestep-pair
#define X3_TB 16           // padded halves per (t,b)

typedef __fp16 fp16x2 __attribute__((ext_vector_type(2)));

// ---------- helpers ----------
#if __has_builtin(__builtin_amdgcn_exp2f)
#define EXP2F(x) __builtin_amdgcn_exp2f(x)
#else
#define EXP2F(x) exp2f(x)
#endif
#if __has_builtin(__builtin_amdgcn_rcpf)
#define RCPF(x) __builtin_amdgcn_rcpf(x)
#else
#define RCPF(x) (1.0f / (x))
#endif

#define KSIG -1.4426950408889634f
#define KTAN -2.8853900817779268f

__device__ __forceinline__ unsigned bperm(int byteidx, unsigned v) {
#if __has_builtin(__builtin_amdgcn_ds_bpermute)
  return (unsigned)__builtin_amdgcn_ds_bpermute(byteidx, (int)v);
#else
  return (unsigned)__shfl((int)v, byteidx >> 2, 64);
#endif
}

template <int Q>
__device__ __forceinline__ float qb(float v) {
#if __has_builtin(__builtin_amdgcn_mov_dpp)
  return __int_as_float(__builtin_amdgcn_mov_dpp(__float_as_int(v), Q * 0x55, 0xF, 0xF, true));
#else
  return __shfl(v, (threadIdx.x & ~3) | Q, 64);
#endif
}

// lane i <- lane i-4 within 16-lane row
__device__ __forceinline__ float row_shr4(float v) {
#if __has_builtin(__builtin_amdgcn_mov_dpp)
  return __int_as_float(__builtin_amdgcn_mov_dpp(__float_as_int(v), 0x114, 0xF, 0xF, true));
#else
  return __shfl(v, (threadIdx.x & 63) - 4, 64);
#endif
}

__device__ __forceinline__ float h16tof(unsigned short u) {
  union { unsigned short s; _Float16 h; } c; c.s = u; return (float)c.h;
}
__device__ __forceinline__ unsigned short f16bits(float f) {
  union { unsigned short s; _Float16 h; } c; c.h = (_Float16)f; return c.s;
}
__device__ __forceinline__ float h16lo(unsigned u) {
  union { unsigned short s; _Float16 h; } c; c.s = (unsigned short)(u & 0xffffu); return (float)c.h;
}
__device__ __forceinline__ float h16hi(unsigned u) {
  union { unsigned short s; _Float16 h; } c; c.s = (unsigned short)(u >> 16); return (float)c.h;
}
__device__ __forceinline__ unsigned pk16(float a, float b) {
#if __has_builtin(__builtin_amdgcn_cvt_pkrtz)
  fp16x2 h = __builtin_amdgcn_cvt_pkrtz(a, b);
  return __builtin_bit_cast(unsigned, h);
#else
  return (unsigned)f16bits(a) | ((unsigned)f16bits(b) << 16);
#endif
}

__device__ __forceinline__ float dot2acc(unsigned a, unsigned b, float c) {
#if __has_builtin(__builtin_amdgcn_fdot2)
  return __builtin_amdgcn_fdot2(__builtin_bit_cast(fp16x2, a), __builtin_bit_cast(fp16x2, b), c, false);
#else
  return fmaf(h16lo(a), h16lo(b), fmaf(h16hi(a), h16hi(b), c));
#endif
}

// 3-deep dot2 chain (6 MACs)
__device__ __forceinline__ float d3(const unsigned* w, const unsigned* h, float init) {
  float a = dot2acc(w[0], h[0], init);
  a = dot2acc(w[1], h[1], a);
  return dot2acc(w[2], h[2], a);
}

// gate nonlin (prescaled input) + c/h update; i,f,g,o quad-broadcast via DPP
__device__ __forceinline__ float nlup(float av, float& cv, float c1, float c0) {
  float e = EXP2F(av);
  float n = fmaf(c1, RCPF(1.f + e), c0);
  float si = qb<0>(n), sf = qb<1>(n), tg = qb<2>(n), so = qb<3>(n);
  cv = fmaf(sf, cv, si * tg);
  float e2 = EXP2F(KTAN * cv);
  return so * fmaf(2.f, RCPF(1.f + e2), -1.f);
}
// pack h into 6 broadcast f16x2 pairs via ds_bpermute (LDS pipe, off-VALU)
__device__ __forceinline__ unsigned packb(float hq, unsigned* hp) {
  float sh = row_shr4(hq);
  unsigned pkv = pk16(sh, hq);
  hp[0] = bperm(16, pkv);  hp[1] = bperm(48, pkv);  hp[2] = bperm(80, pkv);
  hp[3] = bperm(112, pkv); hp[4] = bperm(144, pkv); hp[5] = bperm(176, pkv);
  return pkv;
}

// LDS-drain + barrier WITHOUT vmcnt(0): global stores stay in flight.
#define BARRIER_LGKM() asm volatile("s_waitcnt lgkmcnt(0)\n\ts_barrier" ::: "memory")

// ============================================================================
// Kernel 0: (a) pregate pairs pg2[t2][b][lane48]; (b) packs: w2, WI, w1 -> f16.
// ============================================================================
__global__ __launch_bounds__(64, 4) void pregate_kernel(
    const float* __restrict__ mfcc, const float* __restrict__ Wih,
    const float* __restrict__ bih, const float* __restrict__ bhh,
    const float* __restrict__ w2, const float* __restrict__ WI,
    const float* __restrict__ w1, unsigned* __restrict__ pg2,
    unsigned* __restrict__ w2pk, unsigned* __restrict__ wipk,
    unsigned* __restrict__ w1pk) {
  if (blockIdx.x >= 2048) {  // pack blocks
    const int base = (blockIdx.x - 2048) * 64 + threadIdx.x;
    for (int i = base; i < 4096; i += 512) {  // w2: [32 kp][128 c]
      int kp = i >> 7, c = i & 127;
      float2 v = ((const float2*)w2)[c * 32 + kp];
      w2pk[i] = pk16(v.x, v.y);
    }
    for (int i = base; i < 432; i += 512) {   // WI: [k6][e][6 dp], pairs over d
      int k6 = i / 72, rem = i % 72, e = rem / 6, dp = rem % 6;
      wipk[i] = pk16(WI[k6 * 144 + (2 * dp) * HDIM + e],
                     WI[k6 * 144 + (2 * dp + 1) * HDIM + e]);
    }
    for (int i = base; i < 384; i += 512) {   // w1: [64 ch][6 dp]
      int ch = i / 6, dp = i % 6;
      float2 v = ((const float2*)w1)[ch * 6 + dp];
      w1pk[i] = pk16(v.x, v.y);
    }
    return;
  }
  const int b = blockIdx.x & 255;
  const int tc = blockIdx.x >> 8;  // 0..7, chunks of 64 pairs
  const int lane = threadIdx.x;
  const int j = lane >> 2, q = lane & 3;
  const int jj = (j < HDIM) ? j : (HDIM - 1);
  const int g = q * HDIM + jj;
  const float kqv = (q == 2) ? KTAN : KSIG;
  float w[HDIM];
#pragma unroll
  for (int m = 0; m < HDIM; ++m) w[m] = kqv * Wih[g * HDIM + m];
  const float bias = kqv * (bih[g] + bhh[g]);
  const bool wr = (lane < 48);
  const float* xb = mfcc + (b * T_LEN + tc * 128) * HDIM;
  unsigned* out = pg2 + (unsigned)(tc * 64 * NBATCH + b) * 48 + lane;
  for (int tp = 0; tp < 64; ++tp) {
    float a0 = bias, a1 = bias;
#pragma unroll
    for (int d = 0; d < HDIM; ++d) {
      a0 = fmaf(w[d], xb[d], a0);
      a1 = fmaf(w[d], xb[HDIM + d], a1);
    }
    if (wr) *out = pk16(a0, a1);
    xb += 2 * HDIM;
    out += PAIR_STRIDE;
  }
}

// ============================================================================
// Kernel 1: 3-layer LSTM. 3 waves/block, layer per wave, DEPTH-16 supersteps
// (66 lgkm-only barriers total), hoisted input dots, 2304B LDS dbuf.
// LDS dword map: buffer par at par*256: h0 st[16][8] @0, h1 @128;
// dump @512+lane.
// ============================================================================
__global__ __launch_bounds__(192, 1) void lstm3_kernel(
    const unsigned* __restrict__ pg2,
    const float* __restrict__ Wih, const float* __restrict__ Whh,
    const float* __restrict__ bih, const float* __restrict__ bhh,
    unsigned short* __restrict__ x3) {
  __shared__ __align__(16) unsigned ldsb[576];
  const int b = blockIdx.x;
  const int tid = threadIdx.x;
  const int wid = tid >> 6;
  const int lane = tid & 63;
  const int j = lane >> 2, q = lane & 3;
  const int jj = (j < HDIM) ? j : (HDIM - 1);
  const int g = q * HDIM + jj;
  const float kqv = (q == 2) ? KTAN : KSIG;
  const float c1c = (q == 2) ? 2.0f : 1.0f;
  const float c0c = (q == 2) ? -1.0f : 0.0f;

  const int row = (wid * 48 + g) * HDIM;
  unsigned wihp[6], whhp[6];
#pragma unroll
  for (int m = 0; m < 6; ++m) {
    wihp[m] = pk16(kqv * Wih[row + 2 * m], kqv * Wih[row + 2 * m + 1]);
    whhp[m] = pk16(kqv * Whh[row + 2 * m], kqv * Whh[row + 2 * m + 1]);
  }
  const float biasw = kqv * (bih[wid * 48 + g] + bhh[wid * 48 + g]);

  float cv = 0.f;
  unsigned hown[6] = {0, 0, 0, 0, 0, 0};

  const int grpi = lane >> 3;
  const bool wvalid = ((lane & 7) == 7) && (grpi < 6);
  const int wlayer = (wid == 0) ? 0 : 128;
  const int wsl = wvalid ? (wlayer + grpi) : (512 + lane);
  const int wst = wvalid ? 8 : 0;

  const int lane_src = (lane < 48) ? lane : (44 + (lane & 3));
  const char* pgbase = (const char*)(pg2 + (unsigned)b * 48);
  const unsigned PGB = PAIR_STRIDE * 4;
  const unsigned PGLIM = 513u * PGB;
  uint4 P0 = {0, 0, 0, 0}, P1 = P0, P2 = P0, P3 = P0;
  uint4 A0 = P0, A1 = P0, A2 = P0, A3 = P0;
  unsigned pg_upos = 0;
  if (wid == 0) {
    P0.x = *(const unsigned*)(pgbase + 0 * PGB + lane_src * 4);
    P0.y = *(const unsigned*)(pgbase + 1 * PGB + lane_src * 4);
    P0.z = *(const unsigned*)(pgbase + 2 * PGB + lane_src * 4);
    P0.w = *(const unsigned*)(pgbase + 3 * PGB + lane_src * 4);
    P1.x = *(const unsigned*)(pgbase + 4 * PGB + lane_src * 4);
    P1.y = *(const unsigned*)(pgbase + 5 * PGB + lane_src * 4);
    P1.z = *(const unsigned*)(pgbase + 6 * PGB + lane_src * 4);
    P1.w = *(const unsigned*)(pgbase + 7 * PGB + lane_src * 4);
    P2.x = *(const unsigned*)(pgbase + 8 * PGB + lane_src * 4);
    P2.y = *(const unsigned*)(pgbase + 9 * PGB + lane_src * 4);
    P2.z = *(const unsigned*)(pgbase + 10 * PGB + lane_src * 4);
    P2.w = *(const unsigned*)(pgbase + 11 * PGB + lane_src * 4);
    P3.x = *(const unsigned*)(pgbase + 12 * PGB + lane_src * 4);
    P3.y = *(const unsigned*)(pgbase + 13 * PGB + lane_src * 4);
    P3.z = *(const unsigned*)(pgbase + 14 * PGB + lane_src * 4);
    P3.w = *(const unsigned*)(pgbase + 15 * PGB + lane_src * 4);
    A0.x = *(const unsigned*)(pgbase + 16 * PGB + lane_src * 4);
    A0.y = *(const unsigned*)(pgbase + 17 * PGB + lane_src * 4);
    A0.z = *(const unsigned*)(pgbase + 18 * PGB + lane_src * 4);
    A0.w = *(const unsigned*)(pgbase + 19 * PGB + lane_src * 4);
    A1.x = *(const unsigned*)(pgbase + 20 * PGB + lane_src * 4);
    A1.y = *(const unsigned*)(pgbase + 21 * PGB + lane_src * 4);
    A1.z = *(const unsigned*)(pgbase + 22 * PGB + lane_src * 4);
    A1.w = *(const unsigned*)(pgbase + 23 * PGB + lane_src * 4);
    A2.x = *(const unsigned*)(pgbase + 24 * PGB + lane_src * 4);
    A2.y = *(const unsigned*)(pgbase + 25 * PGB + lane_src * 4);
    A2.z = *(const unsigned*)(pgbase + 26 * PGB + lane_src * 4);
    A2.w = *(const unsigned*)(pgbase + 27 * PGB + lane_src * 4);
    A3.x = *(const unsigned*)(pgbase + 28 * PGB + lane_src * 4);
    A3.y = *(const unsigned*)(pgbase + 29 * PGB + lane_src * 4);
    A3.z = *(const unsigned*)(pgbase + 30 * PGB + lane_src * 4);
    A3.w = *(const unsigned*)(pgbase + 31 * PGB + lane_src * 4);
    pg_upos = 32u * PGB;
  }

  char* x3b = (char*)(x3 + (unsigned)b * X3_TB);
  const int x3_loff = ((j & 1) && j < HDIM) ? (j - 1) * 2 : ((j < HDIM) ? 24 : 28);
  unsigned x3_upos = 0;
  const unsigned X3STEP = NBATCH * X3_TB * 2;

  auto l0_ss = [&](int par, uint4 Pa, uint4 Pb) {
    const int wpb = wvalid ? par * 256 : 0;
    const float pgf[16] = {h16lo(Pa.x), h16hi(Pa.x), h16lo(Pa.y), h16hi(Pa.y),
                           h16lo(Pa.z), h16hi(Pa.z), h16lo(Pa.w), h16hi(Pa.w),
                           h16lo(Pb.x), h16hi(Pb.x), h16lo(Pb.y), h16hi(Pb.y),
                           h16lo(Pb.z), h16hi(Pb.z), h16lo(Pb.w), h16hi(Pb.w)};
#pragma unroll
    for (int st = 0; st < 16; ++st) {
      float a = d3(whhp, hown, pgf[st]) + d3(whhp + 3, hown + 3, 0.f);
      float hq = nlup(a, cv, c1c, c0c);
      unsigned pkv = packb(hq, hown);
      ldsb[wpb + wsl + st * wst] = pkv;
    }
  };
  auto l1_ss = [&](int par) {
    const unsigned* rb = ldsb + (par ^ 1) * 256;
    unsigned hin[16][6];
#pragma unroll
    for (int st = 0; st < 16; ++st) {
      uint4 A = *(const uint4*)(rb + st * 8);
      uint2 B = *(const uint2*)(rb + st * 8 + 4);
      hin[st][0] = A.x; hin[st][1] = A.y; hin[st][2] = A.z;
      hin[st][3] = A.w; hin[st][4] = B.x; hin[st][5] = B.y;
    }
    float aI[16];
#pragma unroll
    for (int st = 0; st < 16; ++st)
      aI[st] = d3(wihp, hin[st], biasw) + d3(wihp + 3, hin[st] + 3, 0.f);
    const int wpb = wvalid ? par * 256 : 0;
#pragma unroll
    for (int st = 0; st < 16; ++st) {
      float a = aI[st] + (d3(whhp, hown, 0.f) + d3(whhp + 3, hown + 3, 0.f));
      float hq = nlup(a, cv, c1c, c0c);
      unsigned pkv = packb(hq, hown);
      ldsb[wpb + wsl + st * wst] = pkv;
    }
  };
  auto l2_ss = [&](int par) {
    const unsigned* rb = ldsb + (par ^ 1) * 256 + 128;
    unsigned hin[16][6];
#pragma unroll
    for (int st = 0; st < 16; ++st) {
      uint4 A = *(const uint4*)(rb + st * 8);
      uint2 B = *(const uint2*)(rb + st * 8 + 4);
      hin[st][0] = A.x; hin[st][1] = A.y; hin[st][2] = A.z;
      hin[st][3] = A.w; hin[st][4] = B.x; hin[st][5] = B.y;
    }
    float aI[16];
#pragma unroll
    for (int st = 0; st < 16; ++st)
      aI[st] = d3(wihp, hin[st], biasw) + d3(wihp + 3, hin[st] + 3, 0.f);
#pragma unroll
    for (int st = 0; st < 16; ++st) {
      float a = aI[st] + (d3(whhp, hown, 0.f) + d3(whhp + 3, hown + 3, 0.f));
      float hq = nlup(a, cv, c1c, c0c);
      unsigned pkv = packb(hq, hown);
      *(unsigned*)(x3b + x3_upos + st * X3STEP + x3_loff) = pkv;
    }
    x3_upos += 16 * X3STEP;
  };

  // phase 0 (par 0): L0 ss0
  if (wid == 0) l0_ss(0, P0, P1);
  BARRIER_LGKM();
  // phase 1 (par 1): L0 ss1 + L1 ss0
  if (wid == 0) l0_ss(1, P2, P3);
  else if (wid == 1) l1_ss(1);
  BARRIER_LGKM();
  // main: phases 2..63 as 31 double-phases
  for (int i = 0; i < 31; ++i) {
    uint4 N0 = {0, 0, 0, 0}, N1 = N0, N2 = N0, N3 = N0;
    if (wid == 0) {
      unsigned o[16];
#pragma unroll
      for (int m = 0; m < 16; ++m) {
        unsigned ov = pg_upos + m * PGB;
        o[m] = ov > PGLIM ? PGLIM : ov;
      }
      N0.x = *(const unsigned*)(pgbase + o[0] + lane_src * 4);
      N0.y = *(const unsigned*)(pgbase + o[1] + lane_src * 4);
      N0.z = *(const unsigned*)(pgbase + o[2] + lane_src * 4);
      N0.w = *(const unsigned*)(pgbase + o[3] + lane_src * 4);
      N1.x = *(const unsigned*)(pgbase + o[4] + lane_src * 4);
      N1.y = *(const unsigned*)(pgbase + o[5] + lane_src * 4);
      N1.z = *(const unsigned*)(pgbase + o[6] + lane_src * 4);
      N1.w = *(const unsigned*)(pgbase + o[7] + lane_src * 4);
      N2.x = *(const unsigned*)(pgbase + o[8] + lane_src * 4);
      N2.y = *(const unsigned*)(pgbase + o[9] + lane_src * 4);
      N2.z = *(const unsigned*)(pgbase + o[10] + lane_src * 4);
      N2.w = *(const unsigned*)(pgbase + o[11] + lane_src * 4);
      N3.x = *(const unsigned*)(pgbase + o[12] + lane_src * 4);
      N3.y = *(const unsigned*)(pgbase + o[13] + lane_src * 4);
      N3.z = *(const unsigned*)(pgbase + o[14] + lane_src * 4);
      N3.w = *(const unsigned*)(pgbase + o[15] + lane_src * 4);
      pg_upos += 16 * PGB;
      l0_ss(0, A0, A1);
    } else if (wid == 1) {
      l1_ss(0);
    } else {
      l2_ss(0);
    }
    BARRIER_LGKM();
    if (wid == 0) l0_ss(1, A2, A3);
    else if (wid == 1) l1_ss(1);
    else l2_ss(1);
    BARRIER_LGKM();
    if (wid == 0) { A0 = N0; A1 = N1; A2 = N2; A3 = N3; }
  }
  // phase 64 (par 0): L1 ss63 + L2 ss62
  if (wid == 1) l1_ss(0);
  else if (wid == 2) l2_ss(0);
  BARRIER_LGKM();
  // phase 65 (par 1): L2 ss63
  if (wid == 2) l2_ss(1);
}

// ============================================================================
// Kernel 2: per-timestep MLP + batch BN + lambda projection. 1 block / t,
// 256 threads, 2 blocks/CU (R13-proven, ~78us). fc1 + WI projection via
// packed-f16 v_dot2 (w1pk / wipk); fc2 via k-paired dot2 from LDS.
// ============================================================================
__global__ __launch_bounds__(256, 2) void mlp_out_kernel(
    const unsigned short* __restrict__ x3, const float* __restrict__ mfcc,
    const unsigned* __restrict__ w1pk, const float* __restrict__ g1,
    const float* __restrict__ be1, const unsigned* __restrict__ w2pk,
    const float* __restrict__ g2, const float* __restrict__ be2,
    const float* __restrict__ w3, const float* __restrict__ b3,
    const unsigned* __restrict__ wipk, float* __restrict__ outp) {
  __shared__ __align__(16) unsigned char smem[53952];
  unsigned* h1p = (unsigned*)smem;            // [32][256] dwords, 32KB
  unsigned* w2p = (unsigned*)(smem + 32768);  // [32][128] dwords, 16KB
  float* p3 = (float*)smem;                   // [8][256][6] f32 alias, 48KB
  float* stp = (float*)(smem + 49152);        // 2KB partials
  float* scsh = (float*)(smem + 51200);       // [128][2] f32, 1KB
  unsigned* wis = (unsigned*)(smem + 52224);  // [432] WI pairs, 1.7KB

  const int t = blockIdx.x;
  const int tid = threadIdx.x;

  // ---- phase 1: stage w2p + wipk ----
  for (int i = tid; i < 1024; i += 256)
    ((uint4*)w2p)[i] = ((const uint4*)w2pk)[i];
  for (int i = tid; i < 432; i += 256) wis[i] = wipk[i];

  // ---- phase 2: fc1 via dot2 on native f16 d-pairs (bias cancels under BN) ----
  {
    const unsigned short* xp = x3 + t * (NBATCH * X3_TB) + tid * X3_TB;
    uint2 u0 = ((const uint2*)xp)[0];
    uint2 u1 = ((const uint2*)xp)[1];
    uint2 u2 = ((const uint2*)xp)[2];
    const unsigned u[6] = {u0.x, u0.y, u1.x, u1.y, u2.x, u2.y};
#pragma unroll 4
    for (int kp = 0; kp < 32; ++kp) {
      const unsigned* wp = w1pk + kp * 12;  // rows 2kp, 2kp+1
      float a0 = dot2acc(wp[0], u[0], 0.f);
      float a1 = dot2acc(wp[6], u[0], 0.f);
#pragma unroll
      for (int dp = 1; dp < 6; ++dp) {
        a0 = dot2acc(wp[dp], u[dp], a0);
        a1 = dot2acc(wp[6 + dp], u[dp], a1);
      }
      h1p[kp * 256 + tid] = pk16(a0, a1);
    }
  }
  __syncthreads();

  // ---- phase 3: BN1 stats; thread=(kp,seg), 32 b each, xor32 + LDS reduce ----
  {
    const int kp = tid & 31, seg = tid >> 5;
    const uint4* rp = (const uint4*)(h1p + kp * 256 + seg * 32);
    float sl = 0.f, sh = 0.f, ql = 0.f, qh = 0.f;
#pragma unroll
    for (int i = 0; i < 8; ++i) {
      uint4 v = rp[(i + kp) & 7];  // rotate to avoid bank conflicts
      float f0 = h16lo(v.x), f1 = h16hi(v.x), f2 = h16lo(v.y), f3 = h16hi(v.y);
      float f4 = h16lo(v.z), f5 = h16hi(v.z), f6 = h16lo(v.w), f7 = h16hi(v.w);
      sl += (f0 + f2) + (f4 + f6);
      sh += (f1 + f3) + (f5 + f7);
      ql = fmaf(f0, f0, ql); ql = fmaf(f2, f2, ql); ql = fmaf(f4, f4, ql); ql = fmaf(f6, f6, ql);
      qh = fmaf(f1, f1, qh); qh = fmaf(f3, f3, qh); qh = fmaf(f5, f5, qh); qh = fmaf(f7, f7, qh);
    }
    sl += __shfl_xor(sl, 32, 64); sh += __shfl_xor(sh, 32, 64);
    ql += __shfl_xor(ql, 32, 64); qh += __shfl_xor(qh, 32, 64);
    if ((tid & 63) < 32) {
      float* sp = stp + kp * 16 + (tid >> 6) * 4;
      sp[0] = sl; sp[1] = sh; sp[2] = ql; sp[3] = qh;
    }
  }
  __syncthreads();
  if (tid < 64) {
    const int kp = tid >> 1, par = tid & 1;
    float s = 0.f, qq = 0.f;
#pragma unroll
    for (int w = 0; w < 4; ++w) {
      s += stp[kp * 16 + w * 4 + par];
      qq += stp[kp * 16 + w * 4 + 2 + par];
    }
    const int ch = 2 * kp + par;
    float mu = s * (1.f / 256.f);
    float var = fmaf(-mu, mu, qq * (1.f / 256.f));
    float sc = g1[ch] * rsqrtf(var + 1e-5f);
    scsh[ch * 2] = sc;
    scsh[ch * 2 + 1] = fmaf(-sc, mu, be1[ch]);
  }
  __syncthreads();
  // ---- phase 3c: apply BN1 + relu in place (thread = b) ----
  {
    unsigned* cp = h1p + tid;
#pragma unroll 8
    for (int kp = 0; kp < 32; ++kp) {
      unsigned v = cp[kp * 256];
      float fl = fmaxf(fmaf(scsh[kp * 4 + 0], h16lo(v), scsh[kp * 4 + 1]), 0.f);
      float fh = fmaxf(fmaf(scsh[kp * 4 + 2], h16hi(v), scsh[kp * 4 + 3]), 0.f);
      cp[kp * 256] = pk16(fl, fh);
    }
  }
  __syncthreads();

  // ---- phase 4: fc2, 8b x 16c per thread, direct pair reads ----
  const int tb = tid & 31, tc2 = tid >> 5;
  const int b0 = tb * 8, cc0 = tc2 * 16;
  float acc[8][16];
#pragma unroll
  for (int bi = 0; bi < 8; ++bi)
#pragma unroll
    for (int ci = 0; ci < 16; ++ci) acc[bi][ci] = 0.f;

  for (int kp = 0; kp < 32; ++kp) {
    const unsigned* hrow = h1p + kp * 256 + b0;
    uint4 a01 = ((const uint4*)hrow)[0];
    uint4 a23 = ((const uint4*)hrow)[1];
    const unsigned ap[8] = {a01.x, a01.y, a01.z, a01.w, a23.x, a23.y, a23.z, a23.w};
    const unsigned* wrow = w2p + kp * 128 + cc0;
#pragma unroll
    for (int wq = 0; wq < 4; ++wq) {
      uint4 wv = ((const uint4*)wrow)[wq];
      const unsigned ww[4] = {wv.x, wv.y, wv.z, wv.w};
#pragma unroll
      for (int bi = 0; bi < 8; ++bi)
#pragma unroll
        for (int cj = 0; cj < 4; ++cj)
          acc[bi][wq * 4 + cj] = dot2acc(ap[bi], ww[cj], acc[bi][wq * 4 + cj]);
    }
  }

  // ---- phase 5: BN2 stats (shuffle-reduce over tb) ----
  {
    float sv[16], qv[16];
#pragma unroll
    for (int ci = 0; ci < 16; ++ci) {
      float s = 0.f, sq = 0.f;
#pragma unroll
      for (int bi = 0; bi < 8; ++bi) {
        s += acc[bi][ci];
        sq = fmaf(acc[bi][ci], acc[bi][ci], sq);
      }
      sv[ci] = s; qv[ci] = sq;
    }
#pragma unroll
    for (int m = 1; m <= 16; m <<= 1) {
#pragma unroll
      for (int ci = 0; ci < 16; ++ci) {
        sv[ci] += __shfl_xor(sv[ci], m, 64);
        qv[ci] += __shfl_xor(qv[ci], m, 64);
      }
    }
    if (tb == 0) {
#pragma unroll
      for (int ci = 0; ci < 16; ++ci) {
        stp[(cc0 + ci) * 2] = sv[ci];
        stp[(cc0 + ci) * 2 + 1] = qv[ci];
      }
    }
  }
  __syncthreads();
  if (tid < 128) {
    float mu = stp[tid * 2] * (1.f / 256.f);
    float var = fmaf(-mu, mu, stp[tid * 2 + 1] * (1.f / 256.f));
    float sc = g2[tid] * rsqrtf(var + 1e-5f);
    scsh[tid * 2] = sc;
    scsh[tid * 2 + 1] = fmaf(-sc, mu, be2[tid]);
  }
  __syncthreads();

  // ---- phase 6: BN2-apply + relu + fc3 partials (fused) ----
  {
    float lam[8][6];
#pragma unroll
    for (int bi = 0; bi < 8; ++bi)
#pragma unroll
      for (int k6 = 0; k6 < 6; ++k6) lam[bi][k6] = 0.f;
#pragma unroll
    for (int ci = 0; ci < 16; ++ci) {
      const float sc = scsh[(cc0 + ci) * 2], shv = scsh[(cc0 + ci) * 2 + 1];
      float wv6[6];
#pragma unroll
      for (int k6 = 0; k6 < 6; ++k6) wv6[k6] = w3[k6 * 128 + cc0 + ci];
#pragma unroll
      for (int bi = 0; bi < 8; ++bi) {
        float v = fmaxf(fmaf(sc, acc[bi][ci], shv), 0.f);
#pragma unroll
        for (int k6 = 0; k6 < 6; ++k6)
          lam[bi][k6] = fmaf(v, wv6[k6], lam[bi][k6]);
      }
    }
#pragma unroll
    for (int bi = 0; bi < 8; ++bi)
#pragma unroll
      for (int k6 = 0; k6 < 6; ++k6)
        p3[(tc2 * 256 + b0 + bi) * 6 + k6] = lam[bi][k6];
  }
  __syncthreads();

  // ---- phase 7: reduce lambda, dot2 projection via packed WI, write out ----
  {
    float lm[6];
#pragma unroll
    for (int k6 = 0; k6 < 6; ++k6) lm[k6] = b3[k6];
#pragma unroll
    for (int tcc = 0; tcc < 8; ++tcc)
#pragma unroll
      for (int k6 = 0; k6 < 6; ++k6) lm[k6] += p3[(tcc * 256 + tid) * 6 + k6];

    const float4* mp = (const float4*)(mfcc + (tid * T_LEN + t) * HDIM);
    float4 m0 = mp[0], m1 = mp[1], m2 = mp[2];
    const float x[HDIM] = {m0.x, m0.y, m0.z, m0.w, m1.x, m1.y,
                           m1.z, m1.w, m2.x, m2.y, m2.z, m2.w};
    unsigned xpk[6];
#pragma unroll
    for (int dp = 0; dp < 6; ++dp) xpk[dp] = pk16(x[2 * dp], x[2 * dp + 1]);
    float o[HDIM];
#pragma unroll
    for (int e = 0; e < HDIM; ++e) o[e] = x[e];
#pragma unroll
    for (int k6 = 0; k6 < 6; ++k6) {
      const unsigned* wrow = wis + k6 * 72;
#pragma unroll
      for (int e = 0; e < HDIM; ++e) {
        float s = dot2acc(xpk[0], wrow[e * 6 + 0], 0.f);
        s = dot2acc(xpk[1], wrow[e * 6 + 1], s);
        s = dot2acc(xpk[2], wrow[e * 6 + 2], s);
        s = dot2acc(xpk[3], wrow[e * 6 + 3], s);
        s = dot2acc(xpk[4], wrow[e * 6 + 4], s);
        s = dot2acc(xpk[5], wrow[e * 6 + 5], s);
        o[e] = fmaf(lm[k6], s, o[e]);
      }
    }
    float4* op4 = (float4*)(outp + (tid * T_LEN + t) * HDIM);
    op4[0] = make_float4(o[0], o[1], o[2], o[3]);
    op4[1] = make_float4(o[4], o[5], o[6], o[7]);
    op4[2] = make_float4(o[8], o[9], o[10], o[11]);
  }
}

// ============================================================================
extern "C" void kernel_launch(void* const* d_in, const int* in_sizes, int n_in,
                              void* d_out, int out_size, void* d_ws, size_t ws_size,
                              hipStream_t stream) {
  const float* mfcc = (const float*)d_in[0];
  const float* Wih = (const float*)d_in[1];
  const float* Whh = (const float*)d_in[2];
  const float* bih = (const float*)d_in[3];
  const float* bhh = (const float*)d_in[4];
  const float* w1 = (const float*)d_in[5];
  const float* g1 = (const float*)d_in[7];
  const float* be1 = (const float*)d_in[8];
  const float* w2 = (const float*)d_in[9];
  const float* g2 = (const float*)d_in[11];
  const float* be2 = (const float*)d_in[12];
  const float* w3 = (const float*)d_in[13];
  const float* b3 = (const float*)d_in[14];
  const float* WI = (const float*)d_in[15];

  // ws: pg2 dwords [514 pairs][256 b][48] = 25,264,128 B;
  //     x3 f16 [1024][256][16] = 8,388,608 B @ 25,264,128;
  //     w2pk [4096] dw @ 33,652,736; wipk [432] dw @ 33,669,120;
  //     w1pk [384] dw @ 33,670,848.
  unsigned* pg2 = (unsigned*)d_ws;
  unsigned short* x3 = (unsigned short*)((char*)d_ws + 25264128);
  unsigned* w2pk = (unsigned*)((char*)d_ws + 33652736);
  unsigned* wipk = (unsigned*)((char*)d_ws + 33669120);
  unsigned* w1pk = (unsigned*)((char*)d_ws + 33670848);
  float* out = (float*)d_out;

  hipLaunchKernelGGL(pregate_kernel, dim3(2056), dim3(64), 0, stream,
                     mfcc, Wih, bih, bhh, w2, WI, w1, pg2, w2pk, wipk, w1pk);
  hipLaunchKernelGGL(lstm3_kernel, dim3(NBATCH), dim3(192), 0, stream,
                     pg2, Wih, Whh, bih, bhh, x3);
  hipLaunchKernelGGL(mlp_out_kernel, dim3(T_LEN), dim3(256), 0, stream,
                     x3, mfcc, w1pk, g1, be1, w2pk, g2, be2, w3, b3, wipk, out);
}